// Round 16
// baseline (255.909 us; speedup 1.0000x reference)
//
#include <hip/hip_runtime.h>

// Problem constants
#define NB 256
#define NDF 768
#define NQ 96
#define NS 361
#define LDP 392       // K2 attn LDS stride (bf16 elems): 784B rows, 16B-aligned
#define WSROW 368     // ws logits row stride (bf16 elems): 184 dwords
#define WS_LOG_BYTES ((size_t)NB * NQ * WSROW * 2)

typedef short bf16x8_t __attribute__((ext_vector_type(8)));
typedef float f32x2_t __attribute__((ext_vector_type(2)));
typedef float f32x4_t __attribute__((ext_vector_type(4)));
typedef float f32x4u_t __attribute__((ext_vector_type(4), aligned(4)));
typedef unsigned int u32x4_t __attribute__((ext_vector_type(4)));

__device__ __forceinline__ unsigned pack_hi(unsigned b_, unsigned a_) {
    return __builtin_amdgcn_perm(b_, a_, 0x07060302u);
}
__device__ __forceinline__ unsigned short f2bf(float x) {   // RNE
    unsigned u = __float_as_uint(x);
    u += 0x7FFFu + ((u >> 16) & 1u);
    return (unsigned short)(u >> 16);
}
__device__ __forceinline__ float bf2f(unsigned short h) {
    return __uint_as_float(((unsigned)h) << 16);
}

// split-bf16 convert: 8 fp32 -> hi bf16x8 (trunc) + lo bf16x8 (residual, trunc)
__device__ __forceinline__ void cvt8(const float* x, bf16x8_t& hi, bf16x8_t& lo) {
    unsigned uh[8]; float fl[8];
#pragma unroll
    for (int j = 0; j < 8; ++j) {
        unsigned u = __float_as_uint(x[j]);
        uh[j] = u;
        fl[j] = x[j] - __uint_as_float(u & 0xFFFF0000u);
    }
    u32x4_t h, l;
    h[0] = pack_hi(uh[1], uh[0]); h[1] = pack_hi(uh[3], uh[2]);
    h[2] = pack_hi(uh[5], uh[4]); h[3] = pack_hi(uh[7], uh[6]);
    l[0] = pack_hi(__float_as_uint(fl[1]), __float_as_uint(fl[0]));
    l[1] = pack_hi(__float_as_uint(fl[3]), __float_as_uint(fl[2]));
    l[2] = pack_hi(__float_as_uint(fl[5]), __float_as_uint(fl[4]));
    l[3] = pack_hi(__float_as_uint(fl[7]), __float_as_uint(fl[6]));
    hi = __builtin_bit_cast(bf16x8_t, h);
    lo = __builtin_bit_cast(bf16x8_t, l);
}

// Raw asm VMEM: volatile => issue order pinned, outputs cannot be sunk.
#define GLD(D, A)       asm volatile("global_load_dword %0, %1, off" : "=v"(D) : "v"(A))
#define GLDO(D, A, O)   asm volatile("global_load_dword %0, %1, off offset:" #O : "=v"(D) : "v"(A))
#define GLD2(D, A)      asm volatile("global_load_dwordx2 %0, %1, off" : "=v"(D) : "v"(A))
#define GLD2O(D, A, O)  asm volatile("global_load_dwordx2 %0, %1, off offset:" #O : "=v"(D) : "v"(A))
#define VMWAIT_(N) { asm volatile("s_waitcnt vmcnt(" #N ")"); __builtin_amdgcn_sched_barrier(0); }
#define VMWAIT(N) VMWAIT_(N)

// ================= K1: GEMM1 (split-bf16) + softmax over q =================
// BARRIER-FREE: no LDS, no __syncthreads. Each wave independently loads its own
// Q A-fragments straight from global (48 dwords/chunk off ONE base; the 6 waves
// of a block read IDENTICAL addresses -> L2 hits; XCD-pairing keeps the batch's
// 2 blocks on one L2) and ctx B-fragments as paired dwordx2 (8/chunk, 1-ahead
// asm FIFO, constant vmcnt(8)). Wave-level TLP hides what the FIFO doesn't:
// stalls no longer gang across waves (this was K1's ~3.1 vs K2's 5.3 TB/s gap).
// grid NB*2 (batch, s-half of 192), 384 thr = 6 waves; wave: 96q x 32s
// (interleaved col pairs 2ll, 2ll+1).
// MODE 1: bf16 logits2 -> ws.  MODE 0: softmaxq*4 fp32 -> Aout (fallback).
template<int MODE>
__global__ __launch_bounds__(384, 3) void k1_gemm1_softmaxq(
    const float* __restrict__ Qg, const float* __restrict__ Cg,
    unsigned short* __restrict__ WsLog, float* __restrict__ AoutF)
{
    // XCD-pairing swizzle (grid 512 = 8 xcd * 32 batch-groups * 2 halves)
    const int x = blockIdx.x;
    const int b = (x & 7) * 32 + (x >> 4);
    const int h = (x >> 3) & 1;

    const int tid = threadIdx.x;
    const int wv = tid >> 6;
    const int lane = tid & 63;
    const int ll = lane & 15;
    const int lg = lane >> 4;
    const int s0 = 192 * h;
    const int spRaw = s0 + 32 * wv + 2 * ll;
    const int sp0c  = min(spRaw, NS - 2);
    const bool bsel = (spRaw > NS - 2);

    const float* __restrict__ qg  = Qg + (size_t)b * NDF * NQ;   // [768][96]
    const float* __restrict__ cgl = Cg + (size_t)b * NDF * NS + sp0c;

    f32x4_t acc[6][2];
#pragma unroll
    for (int i = 0; i < 6; ++i)
#pragma unroll
        for (int j = 0; j < 2; ++j) acc[i][j] = (f32x4_t)0.0f;

    float qv[48];          // Q fragments, fp32 (mt*8 + j), j = k-elem
    f32x2_t rcA[8], rcB[8];

// 8 Q loads for fragment MT: rows 32c+8lg+j (j=0..7, stride 384B), col 16*MT+ll.
// Single base per chunk; fragment offset = MT*64 B.
#define QLD(MT) { \
    unsigned long long a_ = qa + (MT) * 64ull; \
    GLD (qv[(MT)*8+0], a_);        GLDO(qv[(MT)*8+1], a_, 384); \
    GLDO(qv[(MT)*8+2], a_, 768);   GLDO(qv[(MT)*8+3], a_, 1152); \
    GLDO(qv[(MT)*8+4], a_, 1536);  GLDO(qv[(MT)*8+5], a_, 1920); \
    GLDO(qv[(MT)*8+6], a_, 2304);  GLDO(qv[(MT)*8+7], a_, 2688); }

#define ISSUE_Q(C) { \
    unsigned long long qa = (unsigned long long)(qg + ((C) * 32 + 8 * lg) * NQ + ll); \
    QLD(0); QLD(1); QLD(2); QLD(3); QLD(4); QLD(5); }

// 8 ctx dwordx2 loads: rows 32C+8lg+j, col pair (sp0c, sp0c+1). Row stride 1444 B.
#define ISSUE_CTX(C, R) { \
    unsigned long long p0 = (unsigned long long)(cgl + (size_t)((C) * 32 + 8 * lg) * NS); \
    unsigned long long p1 = p0 + 3u * 1444u; \
    unsigned long long p2 = p0 + 6u * 1444u; \
    GLD2 (R[0], p0); GLD2O(R[1], p0, 1444); GLD2O(R[2], p0, 2888); \
    GLD2 (R[3], p1); GLD2O(R[4], p1, 1444); GLD2O(R[5], p1, 2888); \
    GLD2 (R[6], p2); GLD2O(R[7], p2, 1444); }

#define CVTMFMA(R) { \
    float xe[8], xo[8]; \
    _Pragma("unroll") \
    for (int j = 0; j < 8; ++j) { \
        xe[j] = bsel ? R[j][1] : R[j][0]; \
        xo[j] = R[j][1]; } \
    bf16x8_t B0h, B0l, B1h, B1l; \
    cvt8(xe, B0h, B0l); \
    cvt8(xo, B1h, B1l); \
    _Pragma("unroll") \
    for (int mt = 0; mt < 6; ++mt) { \
        bf16x8_t Ah, Al; \
        cvt8(&qv[mt * 8], Ah, Al); \
        acc[mt][0] = __builtin_amdgcn_mfma_f32_16x16x32_bf16(Ah, B0h, acc[mt][0], 0, 0, 0); \
        acc[mt][0] = __builtin_amdgcn_mfma_f32_16x16x32_bf16(Ah, B0l, acc[mt][0], 0, 0, 0); \
        acc[mt][0] = __builtin_amdgcn_mfma_f32_16x16x32_bf16(Al, B0h, acc[mt][0], 0, 0, 0); \
        acc[mt][1] = __builtin_amdgcn_mfma_f32_16x16x32_bf16(Ah, B1h, acc[mt][1], 0, 0, 0); \
        acc[mt][1] = __builtin_amdgcn_mfma_f32_16x16x32_bf16(Ah, B1l, acc[mt][1], 0, 0, 0); \
        acc[mt][1] = __builtin_amdgcn_mfma_f32_16x16x32_bf16(Al, B1h, acc[mt][1], 0, 0, 0); } }

// BODYF(c): entry outstanding = [ctx(c):8]. Issue Q(c):48 + ctx(c+1):8;
// vmcnt(8) completes ctx(c)+Q(c), leaves ctx(c+1). Then cvt+MFMA chunk c.
#define BODYF(C, USE, FILL) { \
    ISSUE_Q(C); \
    ISSUE_CTX((C) + 1, FILL); \
    VMWAIT(8); \
    CVTMFMA(USE); }

#define BODYL(C, USE) { \
    ISSUE_Q(C); \
    VMWAIT(0); \
    CVTMFMA(USE); }

    ISSUE_CTX(0, rcA);
    for (int c = 0; c < 22; c += 2) {
        BODYF(c,     rcA, rcB);
        BODYF(c + 1, rcB, rcA);
    }
    BODYF(22, rcA, rcB);
    BODYL(23, rcB);

#undef QLD
#undef ISSUE_Q
#undef ISSUE_CTX
#undef CVTMFMA
#undef BODYF
#undef BODYL

    // softmax over q (per s-col), fold *4; col(s of nt) = s0+32wv+2*ll+nt
#pragma unroll
    for (int nt = 0; nt < 2; ++nt) {
        float m = -3.0e38f;
#pragma unroll
        for (int mt = 0; mt < 6; ++mt)
#pragma unroll
            for (int r = 0; r < 4; ++r) m = fmaxf(m, acc[mt][nt][r]);
        m = fmaxf(m, __shfl_xor(m, 16));
        m = fmaxf(m, __shfl_xor(m, 32));
        float sum = 0.0f;
#pragma unroll
        for (int mt = 0; mt < 6; ++mt)
#pragma unroll
            for (int r = 0; r < 4; ++r) {
                float e = __expf(acc[mt][nt][r] - m);
                acc[mt][nt][r] = e;
                sum += e;
            }
        sum += __shfl_xor(sum, 16);
        sum += __shfl_xor(sum, 32);
        float inv = 4.0f / sum;     // fold TEMP1
#pragma unroll
        for (int mt = 0; mt < 6; ++mt)
#pragma unroll
            for (int r = 0; r < 4; ++r) acc[mt][nt][r] *= inv;
    }

    if constexpr (MODE >= 1) {
        unsigned short* wr = WsLog + (size_t)b * NQ * WSROW;
#pragma unroll
        for (int mt = 0; mt < 6; ++mt)
#pragma unroll
            for (int nt = 0; nt < 2; ++nt)
#pragma unroll
                for (int r = 0; r < 4; ++r) {
                    int q = 16 * mt + 4 * lg + r;
                    int s = s0 + 32 * wv + 2 * ll + nt;
                    if (s < NS) wr[q * WSROW + s] = f2bf(acc[mt][nt][r]);
                }
    } else {
        float* aout = AoutF + (size_t)b * NQ * NS;
#pragma unroll
        for (int mt = 0; mt < 6; ++mt)
#pragma unroll
            for (int nt = 0; nt < 2; ++nt)
#pragma unroll
                for (int r = 0; r < 4; ++r) {
                    int q = 16 * mt + 4 * lg + r;
                    int s = s0 + 32 * wv + 2 * ll + nt;
                    if (s < NS) aout[(size_t)q * NS + s] = acc[mt][nt][r];
                }
    }
}

// ================= K15 (fallback only): in-place softmax over s =================
__global__ __launch_bounds__(256) void k15_softmaxs(float* __restrict__ Aout)
{
    const int b = blockIdx.x;
    const int q = blockIdx.y * 4 + (threadIdx.x >> 6);
    const int lane = threadIdx.x & 63;
    float* __restrict__ row = Aout + ((size_t)b * NQ + q) * NS;
    const int c0 = 6 * lane;

    float v[6];
#pragma unroll
    for (int i = 0; i < 6; ++i) v[i] = (c0 + i < NS) ? row[c0 + i] : -INFINITY;
    float m = v[0];
#pragma unroll
    for (int i = 1; i < 6; ++i) m = fmaxf(m, v[i]);
#pragma unroll
    for (int o = 1; o < 64; o <<= 1) m = fmaxf(m, __shfl_xor(m, o));
    float e[6], sum = 0.0f;
#pragma unroll
    for (int i = 0; i < 6; ++i) { e[i] = __expf(v[i] - m); sum += e[i]; }
#pragma unroll
    for (int o = 1; o < 64; o <<= 1) sum += __shfl_xor(sum, o);
    float inv = 1.0f / sum;
#pragma unroll
    for (int i = 0; i < 6; ++i) if (c0 + i < NS) row[c0 + i] = e[i] * inv;
}

// ================= K2: [fused softmax-s +] GEMM2 (r12, unchanged) =================
// grid NB*4 (batch, d-quarter of 192), 512 thr = 8 waves (dw 0..3 x qw 0..1).
template<bool FUSED>
__global__ __launch_bounds__(512, 4) void k2_gemm2(
    const float* __restrict__ Cg, const unsigned short* __restrict__ WsLog,
    const float* __restrict__ AttnF, float* __restrict__ Wout, float* __restrict__ AoutF)
{
    extern __shared__ char smem2[];
    unsigned short* sP = (unsigned short*)smem2;      // [96][LDP]
    unsigned* sPd = (unsigned*)smem2;                 // dword view, stride 196
    float* sMax = (float*)(smem2 + NQ * LDP * 2);     // [96]
    float* sInv = sMax + NQ;                          // [96]

    const int x = blockIdx.x;
    const int b = (x & 7) * 32 + (x >> 5);
    const int quarter = (x >> 3) & 3;
    const int tid = threadIdx.x;
    const int wv = tid >> 6;
    const int lane = tid & 63;
    const int ll = lane & 15;
    const int lg = lane >> 4;

    if constexpr (FUSED) {
        const unsigned* __restrict__ wsd = (const unsigned*)(WsLog + (size_t)b * NQ * WSROW);
        for (int i = tid; i < NQ * 184; i += 512) {
            int r = i / 184, c = i - r * 184;
            sPd[r * 196 + c] = wsd[i];
        }
        for (int i = tid; i < NQ * 12; i += 512) {
            int r = i / 12, c = i - r * 12;
            sPd[r * 196 + 184 + c] = 0;
        }
        __syncthreads();

        const int l32 = tid & 31;
        const int rbase = tid >> 5;
#pragma unroll
        for (int pass = 0; pass < 6; ++pass) {
            int row = pass * 16 + rbase;
            float m = -3.0e38f;
#pragma unroll
            for (int j = 0; j < 6; ++j) {
                int dw = l32 + 32 * j;
                if (dw < 184) {
                    unsigned u = sPd[row * 196 + dw];
                    float v0 = bf2f((unsigned short)(u & 0xFFFFu));
                    float v1 = bf2f((unsigned short)(u >> 16));
                    if (2 * dw < NS) m = fmaxf(m, v0);
                    if (2 * dw + 1 < NS) m = fmaxf(m, v1);
                }
            }
#pragma unroll
            for (int o = 1; o < 32; o <<= 1) m = fmaxf(m, __shfl_xor(m, o));
            if (l32 == 0) sMax[row] = m;
        }
        __syncthreads();
#pragma unroll
        for (int pass = 0; pass < 6; ++pass) {
            int row = pass * 16 + rbase;
            float m = sMax[row];
            float sum = 0.0f;
#pragma unroll
            for (int j = 0; j < 6; ++j) {
                int dw = l32 + 32 * j;
                if (dw < 184) {
                    unsigned u = sPd[row * 196 + dw];
                    float v0 = bf2f((unsigned short)(u & 0xFFFFu));
                    float v1 = bf2f((unsigned short)(u >> 16));
                    float e0 = (2 * dw < NS) ? __expf(v0 - m) : 0.0f;
                    float e1 = (2 * dw + 1 < NS) ? __expf(v1 - m) : 0.0f;
                    sum += e0 + e1;
                    sPd[row * 196 + dw] = ((unsigned)f2bf(e1) << 16) | (unsigned)f2bf(e0);
                }
            }
#pragma unroll
            for (int o = 1; o < 32; o <<= 1) sum += __shfl_xor(sum, o);
            if (l32 == 0) sInv[row] = sum;
        }
        __syncthreads();
        if (tid < NQ) sInv[tid] = 1.0f / sInv[tid];
        __syncthreads();
        if (quarter == 0) {
            float* aout = AoutF + (size_t)b * NQ * NS;
            for (int i = tid; i < NQ * NS; i += 512) {
                int q = i / NS, s = i - q * NS;
                aout[i] = bf2f(sP[q * LDP + s]) * sInv[q];
            }
        }
    } else {
        const float* __restrict__ attn = AttnF + (size_t)b * NQ * NS;
        for (int i = tid; i < NQ * 181; i += 512) {
            int row = i / 181, p = i - row * 181;
            float x0 = attn[row * NS + 2 * p];
            float x1 = (p < 180) ? attn[row * NS + 2 * p + 1] : 0.0f;
            sPd[row * 196 + p] = pack_hi(__float_as_uint(x1), __float_as_uint(x0));
        }
        for (int i = tid; i < NQ * 15; i += 512) {
            int row = i / 15, p = i - row * 15;
            sPd[row * 196 + 181 + p] = 0;
        }
        __syncthreads();
    }

    f32x4_t acc[3][3];
#pragma unroll
    for (int i = 0; i < 3; ++i)
#pragma unroll
        for (int j = 0; j < 3; ++j) acc[i][j] = (f32x4_t)0.0f;

    const int dw = wv >> 1, qw = wv & 1;
    const float* __restrict__ cq = Cg + (size_t)b * NDF * NS + (size_t)(quarter * 192) * NS;

#pragma unroll
    for (int c = 0; c < 12; ++c) {
        bf16x8_t Bf[3];
#pragma unroll
        for (int nt = 0; nt < 3; ++nt) {
            int row = 16 * (3 * qw + nt) + ll;
            Bf[nt] = *(const bf16x8_t*)&sP[row * LDP + 32 * c + 8 * lg];
        }
#pragma unroll
        for (int i = 0; i < 3; ++i) {
            int d = 16 * (3 * dw + i) + ll;
            const float* ap = cq + (size_t)d * NS + 32 * c + 8 * lg;
            u32x4_t u;
            if (c < 11) {
                f32x4u_t a0 = *(const f32x4u_t*)ap;
                f32x4u_t a1 = *(const f32x4u_t*)(ap + 4);
                u[0] = pack_hi(__float_as_uint(a0[1]), __float_as_uint(a0[0]));
                u[1] = pack_hi(__float_as_uint(a0[3]), __float_as_uint(a0[2]));
                u[2] = pack_hi(__float_as_uint(a1[1]), __float_as_uint(a1[0]));
                u[3] = pack_hi(__float_as_uint(a1[3]), __float_as_uint(a1[2]));
            } else {
                float t[8];
#pragma unroll
                for (int e = 0; e < 8; ++e) {
                    int s = 352 + 8 * lg + e;
                    t[e] = (s < NS) ? ap[e] : 0.0f;
                }
                u[0] = pack_hi(__float_as_uint(t[1]), __float_as_uint(t[0]));
                u[1] = pack_hi(__float_as_uint(t[3]), __float_as_uint(t[2]));
                u[2] = pack_hi(__float_as_uint(t[5]), __float_as_uint(t[4]));
                u[3] = pack_hi(__float_as_uint(t[7]), __float_as_uint(t[6]));
            }
            bf16x8_t Af = __builtin_bit_cast(bf16x8_t, u);
#pragma unroll
            for (int nt = 0; nt < 3; ++nt)
                acc[i][nt] = __builtin_amdgcn_mfma_f32_16x16x32_bf16(Af, Bf[nt], acc[i][nt], 0, 0, 0);
        }
    }

    float* wout = Wout + (size_t)b * NDF * NQ;
    float invq[3];
#pragma unroll
    for (int nt = 0; nt < 3; ++nt) {
        if constexpr (FUSED) invq[nt] = sInv[16 * (3 * qw + nt) + ll];
        else invq[nt] = 1.0f;
    }
#pragma unroll
    for (int i = 0; i < 3; ++i)
#pragma unroll
        for (int nt = 0; nt < 3; ++nt)
#pragma unroll
            for (int r = 0; r < 4; ++r) {
                int d = quarter * 192 + 16 * (3 * dw + i) + 4 * lg + r;
                int q = 16 * (3 * qw + nt) + ll;
                wout[(size_t)d * NQ + q] = acc[i][nt][r] * invq[nt];
            }
}

extern "C" void kernel_launch(void* const* d_in, const int* in_sizes, int n_in,
                              void* d_out, int out_size, void* d_ws, size_t ws_size,
                              hipStream_t stream) {
    const float* Qg = (const float*)d_in[0];
    const float* Cg = (const float*)d_in[1];
    float* Wout = (float*)d_out;
    float* Aout = Wout + (size_t)NB * NDF * NQ;   // outputs: weighted_context, attn_map

    const int smem2 = NQ * LDP * 2 + NQ * 8;      // 76032 B

    if (ws_size >= WS_LOG_BYTES) {
        unsigned short* wsLog = (unsigned short*)d_ws;
        k1_gemm1_softmaxq<1><<<dim3(NB * 2), dim3(384), 0, stream>>>(Qg, Cg, wsLog, nullptr);
        (void)hipFuncSetAttribute((const void*)k2_gemm2<true>,
                                  hipFuncAttributeMaxDynamicSharedMemorySize, smem2);
        k2_gemm2<true><<<dim3(NB * 4), dim3(512), smem2, stream>>>(
            Cg, wsLog, nullptr, Wout, Aout);
    } else {
        k1_gemm1_softmaxq<0><<<dim3(NB * 2), dim3(384), 0, stream>>>(Qg, Cg, nullptr, Aout);
        k15_softmaxs<<<dim3(NB, 24), dim3(256), 0, stream>>>(Aout);
        (void)hipFuncSetAttribute((const void*)k2_gemm2<false>,
                                  hipFuncAttributeMaxDynamicSharedMemorySize, smem2);
        k2_gemm2<false><<<dim3(NB * 4), dim3(512), smem2, stream>>>(
            Cg, nullptr, Aout, Wout, Aout);
    }
}

// Round 18
// 232.474 us; speedup vs baseline: 1.1008x; 1.1008x over previous
//
#include <hip/hip_runtime.h>

// Problem constants
#define NB 256
#define NDF 768
#define NQ 96
#define NS 361
#define LDT 40        // staging stride (bf16 elems): 80B rows
#define LDP 392       // K2 attn LDS stride (bf16 elems): 784B rows, 16B-aligned
#define WSROW 368     // ws logits row stride (bf16 elems): 184 dwords
#define WS_LOG_BYTES ((size_t)NB * NQ * WSROW * 2)

typedef short bf16x8_t __attribute__((ext_vector_type(8)));
typedef float f32x4_t __attribute__((ext_vector_type(4)));
typedef float f32x4u_t __attribute__((ext_vector_type(4), aligned(4)));
typedef unsigned int u32x4_t __attribute__((ext_vector_type(4)));

__device__ __forceinline__ unsigned pack_hi(unsigned b_, unsigned a_) {
    return __builtin_amdgcn_perm(b_, a_, 0x07060302u);
}
__device__ __forceinline__ unsigned short f2bf(float x) {   // RNE
    unsigned u = __float_as_uint(x);
    u += 0x7FFFu + ((u >> 16) & 1u);
    return (unsigned short)(u >> 16);
}
__device__ __forceinline__ float bf2f(unsigned short h) {
    return __uint_as_float(((unsigned)h) << 16);
}

// LDS-only barrier: orders LDS ops; does NOT drain vmcnt.
__device__ __forceinline__ void block_sync_lds() {
    asm volatile("s_waitcnt lgkmcnt(0)" ::: "memory");
    __builtin_amdgcn_s_barrier();
    __builtin_amdgcn_sched_barrier(0);
}

// Raw asm VMEM: volatile => issue order pinned, outputs cannot be sunk.
#define GLD4(D, A) asm volatile("global_load_dwordx4 %0, %1, off" : "=v"(D) : "v"(A))
#define VMWAIT0()  { asm volatile("s_waitcnt vmcnt(0)"); __builtin_amdgcn_sched_barrier(0); }

// ================= K1: GEMM1 (split-bf16) + softmax over q =================
// r18 = r17 (16B dwordx4 loads along contiguous dim + LDS transpose staging)
// with the s=360 boundary-quad fix: clamped quads write R[3] (the element that
// corresponds to s=360 after clamping to NS-4) into all 4 rows; rows for
// s>=361 are fake columns discarded by the s<NS guards downstream.
// grid NB*2 (batch, s-half of 192), 384 thr = 6 waves; wave: 2 s-tiles x 6 q-tiles.
// MODE 1: bf16 logits2 -> ws.  MODE 0: softmaxq*4 fp32 -> Aout (fallback).
template<int MODE>
__global__ __launch_bounds__(384, 3) void k1_gemm1_softmaxq(
    const float* __restrict__ Qg, const float* __restrict__ Cg,
    unsigned short* __restrict__ WsLog, float* __restrict__ AoutF)
{
    __shared__ __align__(16) unsigned short sShi[192 * LDT];
    __shared__ __align__(16) unsigned short sSlo[192 * LDT];
    __shared__ __align__(16) unsigned short sQhi[NQ * LDT];
    __shared__ __align__(16) unsigned short sQlo[NQ * LDT];

    // XCD-pairing swizzle (grid 512 = 8 xcd * 32 batch-groups * 2 halves)
    const int x = blockIdx.x;
    const int b = (x & 7) * 32 + (x >> 4);
    const int h = (x >> 3) & 1;

    const int tid = threadIdx.x;
    const int wv = tid >> 6;
    const int lane = tid & 63;
    const int ll = lane & 15;
    const int lg = lane >> 4;
    const int s0 = 192 * h;

    // ctx staging geometry: 4 tiles, idx = tid + 384j -> k-row kkC, s-quad srow.
    // Clamp keeps dwordx4 in-bounds; qfix marks quads where the clamp shifted
    // the only-valid column (s=360 -> element 3 of the clamped load).
    int kkC[4], srow[4], scl[4];
    bool qfix[4];
#pragma unroll
    for (int j = 0; j < 4; ++j) {
        int idx = tid + 384 * j;
        kkC[j] = idx / 48;
        srow[j] = (idx % 48) * 4;
        int sAbs = s0 + srow[j];
        scl[j] = min(sAbs, NS - 4);
        qfix[j] = (sAbs >= NS - 1);   // sAbs==360 (valid, needs R[3]) or fully fake
    }
    // Q staging geometry: 2 tiles, idx = tid + 384j -> k-row kkQ, q-quad qrow
    int kkQ[2], qrow[2];
#pragma unroll
    for (int j = 0; j < 2; ++j) {
        int idx = tid + 384 * j;
        kkQ[j] = idx / 24;
        qrow[j] = (idx % 24) * 4;
    }

    const float* __restrict__ qg = Qg + (size_t)b * NDF * NQ;   // [768][96]
    const float* __restrict__ cg = Cg + (size_t)b * NDF * NS;   // [768][361]

    f32x4_t acc[6][2];
#pragma unroll
    for (int i = 0; i < 6; ++i)
#pragma unroll
        for (int j = 0; j < 2; ++j) acc[i][j] = (f32x4_t)0.0f;

    f32x4_t cR0, cR1, cR2, cR3, qR0, qR1;

#define ISSUE(C) { \
    GLD4(cR0, (unsigned long long)(cg + (size_t)((C) * 32 + kkC[0]) * NS + scl[0])); \
    GLD4(cR1, (unsigned long long)(cg + (size_t)((C) * 32 + kkC[1]) * NS + scl[1])); \
    GLD4(cR2, (unsigned long long)(cg + (size_t)((C) * 32 + kkC[2]) * NS + scl[2])); \
    GLD4(cR3, (unsigned long long)(cg + (size_t)((C) * 32 + kkC[3]) * NS + scl[3])); \
    GLD4(qR0, (unsigned long long)(qg + (size_t)((C) * 32 + kkQ[0]) * NQ + qrow[0])); \
    GLD4(qR1, (unsigned long long)(qg + (size_t)((C) * 32 + kkQ[1]) * NQ + qrow[1])); }

// write one f32x4 (4 consecutive rows' worth) transposed into hi/lo tiles.
// FIXQ: boundary-quad flag -> use R[3] for every row (row s=360 gets the right
// value; rows s>=361 are fake and discarded later).
#define WR4(R, ROWB, COL, DH, DL, FIXQ) { \
    int cg_ = (COL) >> 3, co_ = (COL) & 7; \
    _Pragma("unroll") \
    for (int e = 0; e < 4; ++e) { \
        int row = (ROWB) + e; \
        float v_ = (FIXQ) ? R[3] : R[e]; \
        unsigned u = __float_as_uint(v_); \
        unsigned short hi_ = (unsigned short)(u >> 16); \
        float lf = v_ - bf2f(hi_); \
        unsigned short lo_ = (unsigned short)(__float_as_uint(lf) >> 16); \
        int cs = ((cg_ ^ ((row >> 3) & 3)) << 3) + co_; \
        (DH)[row * LDT + cs] = hi_; \
        (DL)[row * LDT + cs] = lo_; } }

#define CVTWRITE() { \
    VMWAIT0(); \
    WR4(cR0, srow[0], kkC[0], sShi, sSlo, qfix[0]); \
    WR4(cR1, srow[1], kkC[1], sShi, sSlo, qfix[1]); \
    WR4(cR2, srow[2], kkC[2], sShi, sSlo, qfix[2]); \
    WR4(cR3, srow[3], kkC[3], sShi, sSlo, qfix[3]); \
    WR4(qR0, qrow[0], kkQ[0], sQhi, sQlo, false); \
    WR4(qR1, qrow[1], kkQ[1], sQhi, sQlo, false); }

#define MFMAPH() { \
    bf16x8_t Bh[2], Bl[2]; \
    _Pragma("unroll") \
    for (int nt = 0; nt < 2; ++nt) { \
        int row = 32 * wv + 16 * nt + ll; \
        int off = row * LDT + 8 * (lg ^ ((row >> 3) & 3)); \
        Bh[nt] = *(const bf16x8_t*)&sShi[off]; \
        Bl[nt] = *(const bf16x8_t*)&sSlo[off]; } \
    _Pragma("unroll") \
    for (int mt = 0; mt < 6; ++mt) { \
        int row = 16 * mt + ll; \
        int off = row * LDT + 8 * (lg ^ ((row >> 3) & 3)); \
        bf16x8_t Ah = *(const bf16x8_t*)&sQhi[off]; \
        bf16x8_t Al = *(const bf16x8_t*)&sQlo[off]; \
        acc[mt][0] = __builtin_amdgcn_mfma_f32_16x16x32_bf16(Ah, Bh[0], acc[mt][0], 0, 0, 0); \
        acc[mt][0] = __builtin_amdgcn_mfma_f32_16x16x32_bf16(Ah, Bl[0], acc[mt][0], 0, 0, 0); \
        acc[mt][0] = __builtin_amdgcn_mfma_f32_16x16x32_bf16(Al, Bh[0], acc[mt][0], 0, 0, 0); \
        acc[mt][1] = __builtin_amdgcn_mfma_f32_16x16x32_bf16(Ah, Bh[1], acc[mt][1], 0, 0, 0); \
        acc[mt][1] = __builtin_amdgcn_mfma_f32_16x16x32_bf16(Ah, Bl[1], acc[mt][1], 0, 0, 0); \
        acc[mt][1] = __builtin_amdgcn_mfma_f32_16x16x32_bf16(Al, Bh[1], acc[mt][1], 0, 0, 0); } }

    // prologue: load + stage chunk 0
    ISSUE(0);
    CVTWRITE();
    block_sync_lds();

#pragma unroll 1
    for (int c = 0; c < 24; ++c) {
        if (c < 23) ISSUE(c + 1);                 // 6 dwordx4 in flight during MFMA
        __builtin_amdgcn_sched_barrier(0);        // pin issue before MFMA
        MFMAPH();
        block_sync_lds();                         // all waves done reading tile
        if (c < 23) {
            CVTWRITE();                           // vmcnt(0) + transpose-write c+1
            block_sync_lds();                     // writes visible
        }
    }

#undef ISSUE
#undef WR4
#undef CVTWRITE
#undef MFMAPH

    // softmax over q (per s-col), fold *4; D layout: col(s)=ll, row(q)=16mt+4lg+r
#pragma unroll
    for (int nt = 0; nt < 2; ++nt) {
        float m = -3.0e38f;
#pragma unroll
        for (int mt = 0; mt < 6; ++mt)
#pragma unroll
            for (int r = 0; r < 4; ++r) m = fmaxf(m, acc[mt][nt][r]);
        m = fmaxf(m, __shfl_xor(m, 16));
        m = fmaxf(m, __shfl_xor(m, 32));
        float sum = 0.0f;
#pragma unroll
        for (int mt = 0; mt < 6; ++mt)
#pragma unroll
            for (int r = 0; r < 4; ++r) {
                float e = __expf(acc[mt][nt][r] - m);
                acc[mt][nt][r] = e;
                sum += e;
            }
        sum += __shfl_xor(sum, 16);
        sum += __shfl_xor(sum, 32);
        float inv = 4.0f / sum;     // fold TEMP1
#pragma unroll
        for (int mt = 0; mt < 6; ++mt)
#pragma unroll
            for (int r = 0; r < 4; ++r) acc[mt][nt][r] *= inv;
    }

    if constexpr (MODE >= 1) {
        unsigned short* wr = WsLog + (size_t)b * NQ * WSROW;
#pragma unroll
        for (int mt = 0; mt < 6; ++mt)
#pragma unroll
            for (int nt = 0; nt < 2; ++nt)
#pragma unroll
                for (int r = 0; r < 4; ++r) {
                    int q = 16 * mt + 4 * lg + r;
                    int s = s0 + 32 * wv + 16 * nt + ll;
                    if (s < NS) wr[q * WSROW + s] = f2bf(acc[mt][nt][r]);
                }
    } else {
        float* aout = AoutF + (size_t)b * NQ * NS;
#pragma unroll
        for (int mt = 0; mt < 6; ++mt)
#pragma unroll
            for (int nt = 0; nt < 2; ++nt)
#pragma unroll
                for (int r = 0; r < 4; ++r) {
                    int q = 16 * mt + 4 * lg + r;
                    int s = s0 + 32 * wv + 16 * nt + ll;
                    if (s < NS) aout[(size_t)q * NS + s] = acc[mt][nt][r];
                }
    }
}

// ================= K15 (fallback only): in-place softmax over s =================
__global__ __launch_bounds__(256) void k15_softmaxs(float* __restrict__ Aout)
{
    const int b = blockIdx.x;
    const int q = blockIdx.y * 4 + (threadIdx.x >> 6);
    const int lane = threadIdx.x & 63;
    float* __restrict__ row = Aout + ((size_t)b * NQ + q) * NS;
    const int c0 = 6 * lane;

    float v[6];
#pragma unroll
    for (int i = 0; i < 6; ++i) v[i] = (c0 + i < NS) ? row[c0 + i] : -INFINITY;
    float m = v[0];
#pragma unroll
    for (int i = 1; i < 6; ++i) m = fmaxf(m, v[i]);
#pragma unroll
    for (int o = 1; o < 64; o <<= 1) m = fmaxf(m, __shfl_xor(m, o));
    float e[6], sum = 0.0f;
#pragma unroll
    for (int i = 0; i < 6; ++i) { e[i] = __expf(v[i] - m); sum += e[i]; }
#pragma unroll
    for (int o = 1; o < 64; o <<= 1) sum += __shfl_xor(sum, o);
    float inv = 1.0f / sum;
#pragma unroll
    for (int i = 0; i < 6; ++i) if (c0 + i < NS) row[c0 + i] = e[i] * inv;
}

// ================= K2: [fused softmax-s +] GEMM2 (r12, unchanged) =================
template<bool FUSED>
__global__ __launch_bounds__(512, 4) void k2_gemm2(
    const float* __restrict__ Cg, const unsigned short* __restrict__ WsLog,
    const float* __restrict__ AttnF, float* __restrict__ Wout, float* __restrict__ AoutF)
{
    extern __shared__ char smem2[];
    unsigned short* sP = (unsigned short*)smem2;      // [96][LDP]
    unsigned* sPd = (unsigned*)smem2;                 // dword view, stride 196
    float* sMax = (float*)(smem2 + NQ * LDP * 2);     // [96]
    float* sInv = sMax + NQ;                          // [96]

    const int x = blockIdx.x;
    const int b = (x & 7) * 32 + (x >> 5);
    const int quarter = (x >> 3) & 3;
    const int tid = threadIdx.x;
    const int wv = tid >> 6;
    const int lane = tid & 63;
    const int ll = lane & 15;
    const int lg = lane >> 4;

    if constexpr (FUSED) {
        const unsigned* __restrict__ wsd = (const unsigned*)(WsLog + (size_t)b * NQ * WSROW);
        for (int i = tid; i < NQ * 184; i += 512) {
            int r = i / 184, c = i - r * 184;
            sPd[r * 196 + c] = wsd[i];
        }
        for (int i = tid; i < NQ * 12; i += 512) {
            int r = i / 12, c = i - r * 12;
            sPd[r * 196 + 184 + c] = 0;
        }
        __syncthreads();

        const int l32 = tid & 31;
        const int rbase = tid >> 5;
#pragma unroll
        for (int pass = 0; pass < 6; ++pass) {
            int row = pass * 16 + rbase;
            float m = -3.0e38f;
#pragma unroll
            for (int j = 0; j < 6; ++j) {
                int dw = l32 + 32 * j;
                if (dw < 184) {
                    unsigned u = sPd[row * 196 + dw];
                    float v0 = bf2f((unsigned short)(u & 0xFFFFu));
                    float v1 = bf2f((unsigned short)(u >> 16));
                    if (2 * dw < NS) m = fmaxf(m, v0);
                    if (2 * dw + 1 < NS) m = fmaxf(m, v1);
                }
            }
#pragma unroll
            for (int o = 1; o < 32; o <<= 1) m = fmaxf(m, __shfl_xor(m, o));
            if (l32 == 0) sMax[row] = m;
        }
        __syncthreads();
#pragma unroll
        for (int pass = 0; pass < 6; ++pass) {
            int row = pass * 16 + rbase;
            float m = sMax[row];
            float sum = 0.0f;
#pragma unroll
            for (int j = 0; j < 6; ++j) {
                int dw = l32 + 32 * j;
                if (dw < 184) {
                    unsigned u = sPd[row * 196 + dw];
                    float v0 = bf2f((unsigned short)(u & 0xFFFFu));
                    float v1 = bf2f((unsigned short)(u >> 16));
                    float e0 = (2 * dw < NS) ? __expf(v0 - m) : 0.0f;
                    float e1 = (2 * dw + 1 < NS) ? __expf(v1 - m) : 0.0f;
                    sum += e0 + e1;
                    sPd[row * 196 + dw] = ((unsigned)f2bf(e1) << 16) | (unsigned)f2bf(e0);
                }
            }
#pragma unroll
            for (int o = 1; o < 32; o <<= 1) sum += __shfl_xor(sum, o);
            if (l32 == 0) sInv[row] = sum;
        }
        __syncthreads();
        if (tid < NQ) sInv[tid] = 1.0f / sInv[tid];
        __syncthreads();
        if (quarter == 0) {
            float* aout = AoutF + (size_t)b * NQ * NS;
            for (int i = tid; i < NQ * NS; i += 512) {
                int q = i / NS, s = i - q * NS;
                aout[i] = bf2f(sP[q * LDP + s]) * sInv[q];
            }
        }
    } else {
        const float* __restrict__ attn = AttnF + (size_t)b * NQ * NS;
        for (int i = tid; i < NQ * 181; i += 512) {
            int row = i / 181, p = i - row * 181;
            float x0 = attn[row * NS + 2 * p];
            float x1 = (p < 180) ? attn[row * NS + 2 * p + 1] : 0.0f;
            sPd[row * 196 + p] = pack_hi(__float_as_uint(x1), __float_as_uint(x0));
        }
        for (int i = tid; i < NQ * 15; i += 512) {
            int row = i / 15, p = i - row * 15;
            sPd[row * 196 + 181 + p] = 0;
        }
        __syncthreads();
    }

    f32x4_t acc[3][3];
#pragma unroll
    for (int i = 0; i < 3; ++i)
#pragma unroll
        for (int j = 0; j < 3; ++j) acc[i][j] = (f32x4_t)0.0f;

    const int dw = wv >> 1, qw = wv & 1;
    const float* __restrict__ cq = Cg + (size_t)b * NDF * NS + (size_t)(quarter * 192) * NS;

#pragma unroll
    for (int c = 0; c < 12; ++c) {
        bf16x8_t Bf[3];
#pragma unroll
        for (int nt = 0; nt < 3; ++nt) {
            int row = 16 * (3 * qw + nt) + ll;
            Bf[nt] = *(const bf16x8_t*)&sP[row * LDP + 32 * c + 8 * lg];
        }
#pragma unroll
        for (int i = 0; i < 3; ++i) {
            int d = 16 * (3 * dw + i) + ll;
            const float* ap = cq + (size_t)d * NS + 32 * c + 8 * lg;
            u32x4_t u;
            if (c < 11) {
                f32x4u_t a0 = *(const f32x4u_t*)ap;
                f32x4u_t a1 = *(const f32x4u_t*)(ap + 4);
                u[0] = pack_hi(__float_as_uint(a0[1]), __float_as_uint(a0[0]));
                u[1] = pack_hi(__float_as_uint(a0[3]), __float_as_uint(a0[2]));
                u[2] = pack_hi(__float_as_uint(a1[1]), __float_as_uint(a1[0]));
                u[3] = pack_hi(__float_as_uint(a1[3]), __float_as_uint(a1[2]));
            } else {
                float t[8];
#pragma unroll
                for (int e = 0; e < 8; ++e) {
                    int s = 352 + 8 * lg + e;
                    t[e] = (s < NS) ? ap[e] : 0.0f;
                }
                u[0] = pack_hi(__float_as_uint(t[1]), __float_as_uint(t[0]));
                u[1] = pack_hi(__float_as_uint(t[3]), __float_as_uint(t[2]));
                u[2] = pack_hi(__float_as_uint(t[5]), __float_as_uint(t[4]));
                u[3] = pack_hi(__float_as_uint(t[7]), __float_as_uint(t[6]));
            }
            bf16x8_t Af = __builtin_bit_cast(bf16x8_t, u);
#pragma unroll
            for (int nt = 0; nt < 3; ++nt)
                acc[i][nt] = __builtin_amdgcn_mfma_f32_16x16x32_bf16(Af, Bf[nt], acc[i][nt], 0, 0, 0);
        }
    }

    float* wout = Wout + (size_t)b * NDF * NQ;
    float invq[3];
#pragma unroll
    for (int nt = 0; nt < 3; ++nt) {
        if constexpr (FUSED) invq[nt] = sInv[16 * (3 * qw + nt) + ll];
        else invq[nt] = 1.0f;
    }
#pragma unroll
    for (int i = 0; i < 3; ++i)
#pragma unroll
        for (int nt = 0; nt < 3; ++nt)
#pragma unroll
            for (int r = 0; r < 4; ++r) {
                int d = quarter * 192 + 16 * (3 * dw + i) + 4 * lg + r;
                int q = 16 * (3 * qw + nt) + ll;
                wout[(size_t)d * NQ + q] = acc[i][nt][r] * invq[nt];
            }
}

extern "C" void kernel_launch(void* const* d_in, const int* in_sizes, int n_in,
                              void* d_out, int out_size, void* d_ws, size_t ws_size,
                              hipStream_t stream) {
    const float* Qg = (const float*)d_in[0];
    const float* Cg = (const float*)d_in[1];
    float* Wout = (float*)d_out;
    float* Aout = Wout + (size_t)NB * NDF * NQ;   // outputs: weighted_context, attn_map

    const int smem2 = NQ * LDP * 2 + NQ * 8;      // 76032 B

    if (ws_size >= WS_LOG_BYTES) {
        unsigned short* wsLog = (unsigned short*)d_ws;
        k1_gemm1_softmaxq<1><<<dim3(NB * 2), dim3(384), 0, stream>>>(Qg, Cg, wsLog, nullptr);
        (void)hipFuncSetAttribute((const void*)k2_gemm2<true>,
                                  hipFuncAttributeMaxDynamicSharedMemorySize, smem2);
        k2_gemm2<true><<<dim3(NB * 4), dim3(512), smem2, stream>>>(
            Cg, wsLog, nullptr, Wout, Aout);
    } else {
        k1_gemm1_softmaxq<0><<<dim3(NB * 2), dim3(384), 0, stream>>>(Qg, Cg, nullptr, Aout);
        k15_softmaxs<<<dim3(NB, 24), dim3(256), 0, stream>>>(Aout);
        (void)hipFuncSetAttribute((const void*)k2_gemm2<false>,
                                  hipFuncAttributeMaxDynamicSharedMemorySize, smem2);
        k2_gemm2<false><<<dim3(NB * 4), dim3(512), smem2, stream>>>(
            Cg, nullptr, Aout, Wout, Aout);
    }
}

// Round 19
// 206.601 us; speedup vs baseline: 1.2387x; 1.1252x over previous
//
#include <hip/hip_runtime.h>

// Problem constants
#define NB 256
#define NDF 768
#define NQ 96
#define NS 361
#define LDT 40        // Q staging stride (bf16 elems): 80B rows
#define LDP 392       // K2 attn LDS stride (bf16 elems): 784B rows, 16B-aligned
#define WSROW 368     // ws logits row stride (bf16 elems): 184 dwords, 16B-aligned
#define WS_LOG_BYTES ((size_t)NB * NQ * WSROW * 2)

typedef short bf16x8_t __attribute__((ext_vector_type(8)));
typedef float f32x4_t __attribute__((ext_vector_type(4)));
typedef float f32x4u_t __attribute__((ext_vector_type(4), aligned(4)));
typedef unsigned int u32x4_t __attribute__((ext_vector_type(4)));

__device__ __forceinline__ unsigned pack_hi(unsigned b_, unsigned a_) {
    return __builtin_amdgcn_perm(b_, a_, 0x07060302u);
}
__device__ __forceinline__ unsigned short f2bf(float x) {   // RNE
    unsigned u = __float_as_uint(x);
    u += 0x7FFFu + ((u >> 16) & 1u);
    return (unsigned short)(u >> 16);
}
__device__ __forceinline__ float bf2f(unsigned short h) {
    return __uint_as_float(((unsigned)h) << 16);
}

// split-bf16 convert: 8 fp32 -> hi bf16x8 (trunc) + lo bf16x8 (residual, trunc)
__device__ __forceinline__ void cvt8(const float* x, bf16x8_t& hi, bf16x8_t& lo) {
    unsigned uh[8]; float fl[8];
#pragma unroll
    for (int j = 0; j < 8; ++j) {
        unsigned u = __float_as_uint(x[j]);
        uh[j] = u;
        fl[j] = x[j] - __uint_as_float(u & 0xFFFF0000u);
    }
    u32x4_t h, l;
    h[0] = pack_hi(uh[1], uh[0]); h[1] = pack_hi(uh[3], uh[2]);
    h[2] = pack_hi(uh[5], uh[4]); h[3] = pack_hi(uh[7], uh[6]);
    l[0] = pack_hi(__float_as_uint(fl[1]), __float_as_uint(fl[0]));
    l[1] = pack_hi(__float_as_uint(fl[3]), __float_as_uint(fl[2]));
    l[2] = pack_hi(__float_as_uint(fl[5]), __float_as_uint(fl[4]));
    l[3] = pack_hi(__float_as_uint(fl[7]), __float_as_uint(fl[6]));
    hi = __builtin_bit_cast(bf16x8_t, h);
    lo = __builtin_bit_cast(bf16x8_t, l);
}

// LDS-only barrier: orders LDS ops; does NOT drain vmcnt (asm loads stay in flight).
__device__ __forceinline__ void block_sync_lds() {
    asm volatile("s_waitcnt lgkmcnt(0)" ::: "memory");
    __builtin_amdgcn_s_barrier();
    __builtin_amdgcn_sched_barrier(0);
}

// Raw asm loads: volatile => issue order pinned, outputs cannot be sunk/rematerialized.
#define GLD(D, A)     asm volatile("global_load_dword %0, %1, off" : "=v"(D) : "v"(A))
#define GLDO(D, A, O) asm volatile("global_load_dword %0, %1, off offset:" #O : "=v"(D) : "v"(A))
// Counted wait + scheduling fence (rule #18: consumers must not hoist past the wait).
#define VMWAIT(N) { asm volatile("s_waitcnt vmcnt(" #N ")"); __builtin_amdgcn_sched_barrier(0); }

// ================= K1: GEMM1 (split-bf16) + softmax over q =================
// grid NB*2 (batch, s-half of 192), 384 thr = 6 waves; wave: 2 s-tiles x 6 q-tiles.
// Software pipeline with manual vmcnt FIFO accounting (ONLY asm VMEM in the loop):
//   enter iter c: in-flight = [ctx(c):16]
//   issue Q(c+1):8, ctx(c+1):16      -> [ctx(c)16, Q8, ctx16] = 40
//   vmcnt(24)  => ctx(c) complete    -> MFMA on ctx(c)
//   vmcnt(16)  => Q(c+1) complete    -> stage Q -> lgkm barrier
// Q LDS tile XOR-swizzled (col8 ^= (row>>3)&3): stores & reads both <=2-way banks.
template<int MODE>
__global__ __launch_bounds__(384, 3) void k1_gemm1_softmaxq(
    const float* __restrict__ Qg, const float* __restrict__ Cg,
    unsigned short* __restrict__ WsLog, float* __restrict__ AoutF)
{
    __shared__ __align__(16) unsigned short sQhi[2][NQ * LDT];
    __shared__ __align__(16) unsigned short sQlo[2][NQ * LDT];

    // XCD-pairing swizzle (grid 512 = 8 xcd * 32 batch-groups * 2 halves)
    const int x = blockIdx.x;
    const int b = (x & 7) * 32 + (x >> 4);
    const int h = (x >> 3) & 1;

    const int tid = threadIdx.x;
    const int wv = tid >> 6;
    const int lane = tid & 63;
    const int ll = lane & 15;
    const int lg = lane >> 4;
    const int llh = (ll >> 3) & 1;
    const int s0 = 192 * h;
    const int qq = tid % 96;
    const int koct = tid / 96;         // 0..3
    const int sc0 = min(s0 + 32 * wv + ll, NS - 1);
    const int sc1 = min(s0 + 32 * wv + 16 + ll, NS - 1);
    // swizzled Q-tile store offset (shorts): row=qq, col8 = koct ^ ((qq>>3)&3)
    const int stoff = qq * LDT + 8 * (koct ^ ((qq >> 3) & 3));

    const float* __restrict__ qg = Qg + (size_t)b * NDF * NQ;   // [768][96]
    const float* __restrict__ cg = Cg + (size_t)b * NDF * NS;   // [768][361]

    f32x4_t acc[6][2];
#pragma unroll
    for (int i = 0; i < 6; ++i)
#pragma unroll
        for (int j = 0; j < 2; ++j) acc[i][j] = (f32x4_t)0.0f;

    float qv[8], cA[16], cB[16];

// 8 Q loads: rows K0+8*koct..+7, col qq. Stride NQ*4 = 384 B -> offset immediates.
#define ISSUE_Q(K0) { \
    unsigned long long qa = (unsigned long long)(qg + ((K0) + 8 * koct) * NQ + qq); \
    GLD (qv[0], qa);        GLDO(qv[1], qa, 384); \
    GLDO(qv[2], qa, 768);   GLDO(qv[3], qa, 1152); \
    GLDO(qv[4], qa, 1536);  GLDO(qv[5], qa, 1920); \
    GLDO(qv[6], qa, 2304);  GLDO(qv[7], qa, 2688); }

// 16 ctx loads: rows K0+8*lg..+7, cols sc0 then sc1. Stride NS*4 = 1444 B.
#define ISSUE_CTX(K0, R) { \
    unsigned long long p0 = (unsigned long long)(cg + (size_t)((K0) + 8 * lg) * NS + sc0); \
    unsigned long long p1 = p0 + 3u * NS * 4u; \
    unsigned long long p2 = p0 + 6u * NS * 4u; \
    GLD (R[0], p0); GLDO(R[1], p0, 1444); GLDO(R[2], p0, 2888); \
    GLD (R[3], p1); GLDO(R[4], p1, 1444); GLDO(R[5], p1, 2888); \
    GLD (R[6], p2); GLDO(R[7], p2, 1444); \
    unsigned long long p3 = (unsigned long long)(cg + (size_t)((K0) + 8 * lg) * NS + sc1); \
    unsigned long long p4 = p3 + 3u * NS * 4u; \
    unsigned long long p5 = p3 + 6u * NS * 4u; \
    GLD (R[8],  p3); GLDO(R[9],  p3, 1444); GLDO(R[10], p3, 2888); \
    GLD (R[11], p4); GLDO(R[12], p4, 1444); GLDO(R[13], p4, 2888); \
    GLD (R[14], p5); GLDO(R[15], p5, 1444); }

#define STAGEQ(CUR) { \
    bf16x8_t qh, ql; \
    cvt8(qv, qh, ql); \
    *(bf16x8_t*)&sQhi[CUR][stoff] = qh; \
    *(bf16x8_t*)&sQlo[CUR][stoff] = ql; }

#define MFMAPH(R, CUR) { \
    bf16x8_t B0h, B0l, B1h, B1l; \
    cvt8(R, B0h, B0l); \
    cvt8(R + 8, B1h, B1l); \
    _Pragma("unroll") \
    for (int mt = 0; mt < 6; ++mt) { \
        int ro = (16 * mt + ll) * LDT + 8 * (lg ^ ((2 * mt + llh) & 3)); \
        bf16x8_t Ah = *(const bf16x8_t*)&sQhi[CUR][ro]; \
        bf16x8_t Al = *(const bf16x8_t*)&sQlo[CUR][ro]; \
        acc[mt][0] = __builtin_amdgcn_mfma_f32_16x16x32_bf16(Ah, B0h, acc[mt][0], 0, 0, 0); \
        acc[mt][0] = __builtin_amdgcn_mfma_f32_16x16x32_bf16(Ah, B0l, acc[mt][0], 0, 0, 0); \
        acc[mt][0] = __builtin_amdgcn_mfma_f32_16x16x32_bf16(Al, B0h, acc[mt][0], 0, 0, 0); \
        acc[mt][1] = __builtin_amdgcn_mfma_f32_16x16x32_bf16(Ah, B1h, acc[mt][1], 0, 0, 0); \
        acc[mt][1] = __builtin_amdgcn_mfma_f32_16x16x32_bf16(Ah, B1l, acc[mt][1], 0, 0, 0); \
        acc[mt][1] = __builtin_amdgcn_mfma_f32_16x16x32_bf16(Al, B1h, acc[mt][1], 0, 0, 0); } }

// One pipeline iteration for chunk C (uses USE set, fills FILL set).
#define ITER(C, USE, FILL, CUR, NXT) { \
    ISSUE_Q(((C) + 1) * 32); \
    ISSUE_CTX(((C) + 1) * 32, FILL); \
    VMWAIT(24); \
    MFMAPH(USE, CUR); \
    VMWAIT(16); \
    STAGEQ(NXT); \
    block_sync_lds(); }

    // prologue: in-flight becomes [Q(0):8, ctx(0):16]; vmcnt(16) completes Q(0)
    ISSUE_Q(0);
    ISSUE_CTX(0, cA);
    VMWAIT(16);
    STAGEQ(0);
    block_sync_lds();

    for (int c = 0; c < 22; c += 2) {
        ITER(c,     cA, cB, 0, 1);
        ITER(c + 1, cB, cA, 1, 0);
    }
    ITER(22, cA, cB, 0, 1);   // issues Q(23), ctx(23)->cB; stages Q into buf1
    VMWAIT(0);                // ctx(23) complete
    MFMAPH(cB, 1);

#undef ISSUE_Q
#undef ISSUE_CTX
#undef STAGEQ
#undef MFMAPH
#undef ITER

    // softmax over q (per s-col), fold *4; D layout: col(s)=ll, row(q)=16mt+4lg+r
#pragma unroll
    for (int nt = 0; nt < 2; ++nt) {
        float m = -3.0e38f;
#pragma unroll
        for (int mt = 0; mt < 6; ++mt)
#pragma unroll
            for (int r = 0; r < 4; ++r) m = fmaxf(m, acc[mt][nt][r]);
        m = fmaxf(m, __shfl_xor(m, 16));
        m = fmaxf(m, __shfl_xor(m, 32));
        float sum = 0.0f;
#pragma unroll
        for (int mt = 0; mt < 6; ++mt)
#pragma unroll
            for (int r = 0; r < 4; ++r) {
                float e = __expf(acc[mt][nt][r] - m);
                acc[mt][nt][r] = e;
                sum += e;
            }
        sum += __shfl_xor(sum, 16);
        sum += __shfl_xor(sum, 32);
        float inv = 4.0f / sum;     // fold TEMP1
#pragma unroll
        for (int mt = 0; mt < 6; ++mt)
#pragma unroll
            for (int r = 0; r < 4; ++r) acc[mt][nt][r] *= inv;
    }

    if constexpr (MODE >= 1) {
        unsigned short* wr = WsLog + (size_t)b * NQ * WSROW;
#pragma unroll
        for (int mt = 0; mt < 6; ++mt)
#pragma unroll
            for (int nt = 0; nt < 2; ++nt)
#pragma unroll
                for (int r = 0; r < 4; ++r) {
                    int q = 16 * mt + 4 * lg + r;
                    int s = s0 + 32 * wv + 16 * nt + ll;
                    if (s < NS) wr[q * WSROW + s] = f2bf(acc[mt][nt][r]);
                }
    } else {
        float* aout = AoutF + (size_t)b * NQ * NS;
#pragma unroll
        for (int mt = 0; mt < 6; ++mt)
#pragma unroll
            for (int nt = 0; nt < 2; ++nt)
#pragma unroll
                for (int r = 0; r < 4; ++r) {
                    int q = 16 * mt + 4 * lg + r;
                    int s = s0 + 32 * wv + 16 * nt + ll;
                    if (s < NS) aout[(size_t)q * NS + s] = acc[mt][nt][r];
                }
    }
}

// ================= K15 (fallback only): in-place softmax over s =================
__global__ __launch_bounds__(256) void k15_softmaxs(float* __restrict__ Aout)
{
    const int b = blockIdx.x;
    const int q = blockIdx.y * 4 + (threadIdx.x >> 6);
    const int lane = threadIdx.x & 63;
    float* __restrict__ row = Aout + ((size_t)b * NQ + q) * NS;
    const int c0 = 6 * lane;

    float v[6];
#pragma unroll
    for (int i = 0; i < 6; ++i) v[i] = (c0 + i < NS) ? row[c0 + i] : -INFINITY;
    float m = v[0];
#pragma unroll
    for (int i = 1; i < 6; ++i) m = fmaxf(m, v[i]);
#pragma unroll
    for (int o = 1; o < 64; o <<= 1) m = fmaxf(m, __shfl_xor(m, o));
    float e[6], sum = 0.0f;
#pragma unroll
    for (int i = 0; i < 6; ++i) { e[i] = __expf(v[i] - m); sum += e[i]; }
#pragma unroll
    for (int o = 1; o < 64; o <<= 1) sum += __shfl_xor(sum, o);
    float inv = 1.0f / sum;
#pragma unroll
    for (int i = 0; i < 6; ++i) if (c0 + i < NS) row[c0 + i] = e[i] * inv;
}

// ================= K2: [fused softmax-s +] GEMM2 =================
// grid NB*4 (batch, d-quarter of 192), 512 thr = 8 waves (dw 0..3 x qw 0..1).
template<bool FUSED>
__global__ __launch_bounds__(512, 4) void k2_gemm2(
    const float* __restrict__ Cg, const unsigned short* __restrict__ WsLog,
    const float* __restrict__ AttnF, float* __restrict__ Wout, float* __restrict__ AoutF)
{
    extern __shared__ char smem2[];
    unsigned short* sP = (unsigned short*)smem2;      // [96][LDP]
    unsigned* sPd = (unsigned*)smem2;                 // dword view, stride 196
    float* sMax = (float*)(smem2 + NQ * LDP * 2);     // [96]
    float* sInv = sMax + NQ;                          // [96]

    const int x = blockIdx.x;
    const int b = (x & 7) * 32 + (x >> 5);
    const int quarter = (x >> 3) & 3;
    const int tid = threadIdx.x;
    const int wv = tid >> 6;
    const int lane = tid & 63;
    const int ll = lane & 15;
    const int lg = lane >> 4;

    if constexpr (FUSED) {
        const unsigned* __restrict__ wsd = (const unsigned*)(WsLog + (size_t)b * NQ * WSROW);
        for (int i = tid; i < NQ * 184; i += 512) {
            int r = i / 184, c = i - r * 184;
            sPd[r * 196 + c] = wsd[i];
        }
        for (int i = tid; i < NQ * 12; i += 512) {
            int r = i / 12, c = i - r * 12;
            sPd[r * 196 + 184 + c] = 0;
        }
        __syncthreads();

        const int l32 = tid & 31;
        const int rbase = tid >> 5;
#pragma unroll
        for (int pass = 0; pass < 6; ++pass) {
            int row = pass * 16 + rbase;
            float m = -3.0e38f;
#pragma unroll
            for (int j = 0; j < 6; ++j) {
                int dw = l32 + 32 * j;
                if (dw < 184) {
                    unsigned u = sPd[row * 196 + dw];
                    float v0 = bf2f((unsigned short)(u & 0xFFFFu));
                    float v1 = bf2f((unsigned short)(u >> 16));
                    if (2 * dw < NS) m = fmaxf(m, v0);
                    if (2 * dw + 1 < NS) m = fmaxf(m, v1);
                }
            }
#pragma unroll
            for (int o = 1; o < 32; o <<= 1) m = fmaxf(m, __shfl_xor(m, o));
            if (l32 == 0) sMax[row] = m;
        }
        __syncthreads();
#pragma unroll
        for (int pass = 0; pass < 6; ++pass) {
            int row = pass * 16 + rbase;
            float m = sMax[row];
            float sum = 0.0f;
#pragma unroll
            for (int j = 0; j < 6; ++j) {
                int dw = l32 + 32 * j;
                if (dw < 184) {
                    unsigned u = sPd[row * 196 + dw];
                    float v0 = bf2f((unsigned short)(u & 0xFFFFu));
                    float v1 = bf2f((unsigned short)(u >> 16));
                    float e0 = (2 * dw < NS) ? __expf(v0 - m) : 0.0f;
                    float e1 = (2 * dw + 1 < NS) ? __expf(v1 - m) : 0.0f;
                    sum += e0 + e1;
                    sPd[row * 196 + dw] = ((unsigned)f2bf(e1) << 16) | (unsigned)f2bf(e0);
                }
            }
#pragma unroll
            for (int o = 1; o < 32; o <<= 1) sum += __shfl_xor(sum, o);
            if (l32 == 0) sInv[row] = sum;
        }
        __syncthreads();
        if (tid < NQ) sInv[tid] = 1.0f / sInv[tid];
        __syncthreads();
        if (quarter == 0) {
            float* aout = AoutF + (size_t)b * NQ * NS;
            for (int i = tid; i < NQ * NS; i += 512) {
                int q = i / NS, s = i - q * NS;
                aout[i] = bf2f(sP[q * LDP + s]) * sInv[q];
            }
        }
    } else {
        const float* __restrict__ attn = AttnF + (size_t)b * NQ * NS;
        for (int i = tid; i < NQ * 181; i += 512) {
            int row = i / 181, p = i - row * 181;
            float x0 = attn[row * NS + 2 * p];
            float x1 = (p < 180) ? attn[row * NS + 2 * p + 1] : 0.0f;
            sPd[row * 196 + p] = pack_hi(__float_as_uint(x1), __float_as_uint(x0));
        }
        for (int i = tid; i < NQ * 15; i += 512) {
            int row = i / 15, p = i - row * 15;
            sPd[row * 196 + 181 + p] = 0;
        }
        __syncthreads();
    }

    f32x4_t acc[3][3];
#pragma unroll
    for (int i = 0; i < 3; ++i)
#pragma unroll
        for (int j = 0; j < 3; ++j) acc[i][j] = (f32x4_t)0.0f;

    const int dw = wv >> 1, qw = wv & 1;
    const float* __restrict__ cq = Cg + (size_t)b * NDF * NS + (size_t)(quarter * 192) * NS;

#pragma unroll
    for (int c = 0; c < 12; ++c) {
        bf16x8_t Bf[3];
#pragma unroll
        for (int nt = 0; nt < 3; ++nt) {
            int row = 16 * (3 * qw + nt) + ll;
            Bf[nt] = *(const bf16x8_t*)&sP[row * LDP + 32 * c + 8 * lg];
        }
#pragma unroll
        for (int i = 0; i < 3; ++i) {
            int d = 16 * (3 * dw + i) + ll;
            const float* ap = cq + (size_t)d * NS + 32 * c + 8 * lg;
            u32x4_t u;
            if (c < 11) {
                f32x4u_t a0 = *(const f32x4u_t*)ap;
                f32x4u_t a1 = *(const f32x4u_t*)(ap + 4);
                u[0] = pack_hi(__float_as_uint(a0[1]), __float_as_uint(a0[0]));
                u[1] = pack_hi(__float_as_uint(a0[3]), __float_as_uint(a0[2]));
                u[2] = pack_hi(__float_as_uint(a1[1]), __float_as_uint(a1[0]));
                u[3] = pack_hi(__float_as_uint(a1[3]), __float_as_uint(a1[2]));
            } else {
                float t[8];
#pragma unroll
                for (int e = 0; e < 8; ++e) {
                    int s = 352 + 8 * lg + e;
                    t[e] = (s < NS) ? ap[e] : 0.0f;
                }
                u[0] = pack_hi(__float_as_uint(t[1]), __float_as_uint(t[0]));
                u[1] = pack_hi(__float_as_uint(t[3]), __float_as_uint(t[2]));
                u[2] = pack_hi(__float_as_uint(t[5]), __float_as_uint(t[4]));
                u[3] = pack_hi(__float_as_uint(t[7]), __float_as_uint(t[6]));
            }
            bf16x8_t Af = __builtin_bit_cast(bf16x8_t, u);
#pragma unroll
            for (int nt = 0; nt < 3; ++nt)
                acc[i][nt] = __builtin_amdgcn_mfma_f32_16x16x32_bf16(Af, Bf[nt], acc[i][nt], 0, 0, 0);
        }
    }

    float* wout = Wout + (size_t)b * NDF * NQ;
    float invq[3];
#pragma unroll
    for (int nt = 0; nt < 3; ++nt) {
        if constexpr (FUSED) invq[nt] = sInv[16 * (3 * qw + nt) + ll];
        else invq[nt] = 1.0f;
    }
#pragma unroll
    for (int i = 0; i < 3; ++i)
#pragma unroll
        for (int nt = 0; nt < 3; ++nt)
#pragma unroll
            for (int r = 0; r < 4; ++r) {
                int d = quarter * 192 + 16 * (3 * dw + i) + 4 * lg + r;
                int q = 16 * (3 * qw + nt) + ll;
                wout[(size_t)d * NQ + q] = acc[i][nt][r] * invq[nt];
            }
}

extern "C" void kernel_launch(void* const* d_in, const int* in_sizes, int n_in,
                              void* d_out, int out_size, void* d_ws, size_t ws_size,
                              hipStream_t stream) {
    const float* Qg = (const float*)d_in[0];
    const float* Cg = (const float*)d_in[1];
    float* Wout = (float*)d_out;
    float* Aout = Wout + (size_t)NB * NDF * NQ;   // outputs: weighted_context, attn_map

    const int smem2 = NQ * LDP * 2 + NQ * 8;      // 76032 B

    if (ws_size >= WS_LOG_BYTES) {
        unsigned short* wsLog = (unsigned short*)d_ws;
        k1_gemm1_softmaxq<1><<<dim3(NB * 2), dim3(384), 0, stream>>>(Qg, Cg, wsLog, nullptr);
        (void)hipFuncSetAttribute((const void*)k2_gemm2<true>,
                                  hipFuncAttributeMaxDynamicSharedMemorySize, smem2);
        k2_gemm2<true><<<dim3(NB * 4), dim3(512), smem2, stream>>>(
            Cg, wsLog, nullptr, Wout, Aout);
    } else {
        k1_gemm1_softmaxq<0><<<dim3(NB * 2), dim3(384), 0, stream>>>(Qg, Cg, nullptr, Aout);
        k15_softmaxs<<<dim3(NB, 24), dim3(256), 0, stream>>>(Aout);
        (void)hipFuncSetAttribute((const void*)k2_gemm2<false>,
                                  hipFuncAttributeMaxDynamicSharedMemorySize, smem2);
        k2_gemm2<false><<<dim3(NB * 4), dim3(512), smem2, stream>>>(
            Cg, nullptr, Aout, Wout, Aout);
    }
}